// Round 6
// baseline (200.779 us; speedup 1.0000x reference)
//
#include <hip/hip_runtime.h>
#include <hip/hip_bf16.h>
#include <hip/hip_cooperative_groups.h>

namespace cg = cooperative_groups;

typedef int i32x4 __attribute__((ext_vector_type(4)));

namespace {
constexpr int NB = 4, CINc = 256, Hc = 56, Wc = 56, COUTc = 256;
constexpr int LSP = 56 * 56;           // 3136 output pixels per image
constexpr int MD  = NB * LSP;          // 12544 GEMM rows
constexpr int KT  = 2304;              // 256*9
constexpr int YP = 58, XP = 58;        // padded spatial

constexpr int GRID = 196, NTHR = 512;
constexpr int GSTRIDE = GRID * NTHR;   // 100352

// workspace layout
constexpr size_t OFF_A0 = 4096;                             // after slot arrays
constexpr size_t SZ_ACL = (size_t)NB * YP * XP * 256;       // 3,444,736 (i8)
constexpr size_t OFF_A1 = OFF_A0 + SZ_ACL;
constexpr size_t OFF_BW = OFF_A1 + SZ_ACL;
constexpr size_t SZ_BW  = (size_t)COUTc * KT;               // 589,824 (i8)
constexpr size_t OFF_P0 = OFF_BW + SZ_BW;
constexpr size_t SZ_P   = (size_t)MD * COUTc * 2;           // 6,422,528 (i16)
constexpr size_t OFF_P1 = OFF_P0 + SZ_P;                    // end ~20.3 MB
} // namespace

__device__ __forceinline__ float compute_val(int a, int b, float sa0, float sa1) {
  float q0 = rintf(__fdiv_rn((float)a, sa0));
  q0 = fminf(31.f, fmaxf(-31.f, q0));
  float q1 = rintf(__fdiv_rn((float)b, sa1));
  q1 = fminf(31.f, fmaxf(-31.f, q1));
  float acc = __fadd_rn(__fmul_rn(q0, sa0), __fmul_rn(__fmul_rn(q1, sa1), 4.0f));
  float pe = (float)(a + 4 * b);
  return __fadd_rn(pe, __fsub_rn(acc, pe));
}

__global__ __launch_bounds__(NTHR, 1) void k_fused(const float* __restrict__ x,
                                                   const float* __restrict__ w,
                                                   const float* __restrict__ bias,
                                                   float* __restrict__ out,
                                                   char* __restrict__ ws) {
  cg::grid_group grid = cg::this_grid();

  __shared__ __align__(16) char smem[49280];
  char* sA0 = smem;                       // 16384
  char* sA1 = smem + 16384;               // 16384
  char* sB  = smem + 32768;               // 16384
  float* redf = (float*)(smem + 49152);   // 8 floats
  int*   redi = (int*)(smem + 49216);     // 16 ints

  float* slot_a = (float*)ws;             // [256] per-block absmax(x)
  int*   slot0  = (int*)(ws + 1024);      // [256] per-block max|p0|
  int*   slot1  = (int*)(ws + 2048);      // [256] per-block max|p1|
  float* slot_v = (float*)(ws + 3072);    // [256] per-block max|val|
  char*  a0 = ws + OFF_A0;
  char*  a1 = ws + OFF_A1;
  char*  bw = ws + OFF_BW;
  short* p0 = (short*)(ws + OFF_P0);
  short* p1 = (short*)(ws + OFF_P1);

  const int tid = threadIdx.x, bid = blockIdx.x;
  const int gtid = bid * NTHR + tid;
  const int lane = tid & 63, wv = tid >> 6;

  // ================= P0: zero a0/a1, binarize W, absmax(x) partials =================
  {
    int4* pz = (int4*)a0;                       // a0 and a1 are contiguous
    const int nz = (int)(2 * SZ_ACL / 16);      // 430,592
    for (int i = gtid; i < nz; i += GSTRIDE) pz[i] = int4{0, 0, 0, 0};
  }
  for (int co = bid; co < COUTc; co += GRID) {  // binarize+reorder W, sB as scratch
    for (int t = tid; t < KT; t += NTHR)        // t = cin*9 + s
      sB[t] = w[(size_t)co * KT + t] >= 0.f ? (char)1 : (char)-1;
    __syncthreads();
    char4* dst4 = (char4*)(bw + (size_t)co * KT);
    for (int j4 = tid; j4 < KT / 4; j4 += NTHR) {
      char4 v; char* vp = (char*)&v;
#pragma unroll
      for (int e = 0; e < 4; ++e) {
        int j = j4 * 4 + e;                     // j = s*256 + cin
        vp[e] = sB[(j & 255) * 9 + (j >> 8)];
      }
      dst4[j4] = v;
    }
    __syncthreads();
  }
  {
    float mx = 0.f;
    const float4* x4 = (const float4*)x;
    const int n4 = NB * CINc * Hc * Wc / 4;     // 802,816 -> 8 iters
    for (int i = gtid; i < n4; i += GSTRIDE) {
      float4 v = x4[i];
      mx = fmaxf(mx, fmaxf(fmaxf(fabsf(v.x), fabsf(v.y)), fmaxf(fabsf(v.z), fabsf(v.w))));
    }
#pragma unroll
    for (int off = 32; off; off >>= 1) mx = fmaxf(mx, __shfl_xor(mx, off));
    if (lane == 0) redf[wv] = mx;
    __syncthreads();
    if (tid == 0) {
      float m = 0.f;
#pragma unroll
      for (int i = 0; i < 8; ++i) m = fmaxf(m, redf[i]);
      slot_a[bid] = m;
    }
  }
  grid.sync();

  // ================= P1: quantize -> i8 DAC slices, channels-last padded =================
  float gmax = 0.f;
  for (int i = 0; i < GRID; ++i) gmax = fmaxf(gmax, slot_a[i]);
  const float sx = fmaxf(__fdiv_rn(gmax, 7.0f), 1e-12f);
  for (int nh = bid; nh < NB * Hc; nh += GRID) {
    const int n = nh / Hc, h = nh % Hc;
    char* t0 = sA0;                             // 14336 bytes each
    char* t1 = sA1;
    const int c = tid & 255, half = tid >> 8;   // half: 28 w's each
    const float2* src = (const float2*)(x + (((size_t)n * CINc + c) * Hc + h) * Wc + half * 28);
#pragma unroll
    for (int j = 0; j < 14; ++j) {
      float2 v = src[j];
      float arr[2] = {v.x, v.y};
#pragma unroll
      for (int e = 0; e < 2; ++e) {
        float qf = rintf(__fdiv_rn(arr[e], sx));
        qf = fminf(7.f, fmaxf(-7.f, qf));
        int qi = (int)qf;
        int mag = qi < 0 ? -qi : qi;
        int s0 = mag & 3, s1 = mag >> 2;
        if (qi < 0) { s0 = -s0; s1 = -s1; }
        int ww = half * 28 + j * 2 + e;
        t0[ww * 256 + c] = (char)s0;
        t1[ww * 256 + c] = (char)s1;
      }
    }
    __syncthreads();
    for (int idx = tid; idx < 896; idx += NTHR) {
      int wr = idx >> 4, c16 = (idx & 15) << 4;
      int4 v0 = *(const int4*)&t0[wr * 256 + c16];
      int4 v1 = *(const int4*)&t1[wr * 256 + c16];
      size_t dst = (((size_t)n * YP + (h + 1)) * XP + (wr + 1)) * 256 + c16;
      *(int4*)&a0[dst] = v0;
      *(int4*)&a1[dst] = v1;
    }
    __syncthreads();
  }
  grid.sync();

  // ================= P2: dual i8 GEMM 128x128 tile per block =================
  {
    const int wm = (tid >> 6) >> 1, wn = (tid >> 6) & 1;    // 4x2 waves, 32x64 each
    const int nblk = bid & 1, mblk = bid >> 1;
    const int m0 = mblk * 128, n0 = nblk * 128;

    i32x4 acc0[2][4] = {};
    i32x4 acc1[2][4] = {};

    const int trow = tid >> 3;          // 0..63
    const int cb = (tid & 7) * 16;      // 16B seg within 128B row

    int rn[2], roh[2], rww[2];
#pragma unroll
    for (int p = 0; p < 2; ++p) {
      int m = m0 + p * 64 + trow;
      rn[p] = m / LSP; int l = m - rn[p] * LSP;
      roh[p] = l / 56; rww[p] = l - roh[p] * 56;
    }

#pragma unroll 1
    for (int kb = 0; kb < KT / 128; ++kb) {       // 18 iters, K-step 128
      const int slab = kb >> 1;
      const int kh = slab / 3, kw = slab - (slab / 3) * 3;
      const int c0 = (kb & 1) << 7;
      __syncthreads();
#pragma unroll
      for (int p = 0; p < 2; ++p) {
        const int r = p * 64 + trow;
        const int dst = r * 128 + (cb ^ ((r & 7) << 4));
        size_t ga = (((size_t)rn[p] * YP + (roh[p] + kh)) * XP + (rww[p] + kw)) * 256 + c0;
        *(int4*)(sA0 + dst) = *(const int4*)(a0 + ga + cb);
        *(int4*)(sA1 + dst) = *(const int4*)(a1 + ga + cb);
        size_t gb = (size_t)(n0 + r) * KT + kb * 128;
        *(int4*)(sB + dst) = *(const int4*)(bw + gb + cb);
      }
      __syncthreads();
#pragma unroll
      for (int ks = 0; ks < 2; ++ks) {
        const int kbyte = ks * 64 + ((lane >> 4) << 4);
        i32x4 bfr[4], af0[2], af1[2];
#pragma unroll
        for (int r = 0; r < 4; ++r) {
          int rr = wn * 64 + r * 16 + (lane & 15);
          bfr[r] = *(const i32x4*)(sB + rr * 128 + (kbyte ^ ((rr & 7) << 4)));
        }
#pragma unroll
        for (int q = 0; q < 2; ++q) {
          int rr = wm * 32 + q * 16 + (lane & 15);
          int off = rr * 128 + (kbyte ^ ((rr & 7) << 4));
          af0[q] = *(const i32x4*)(sA0 + off);
          af1[q] = *(const i32x4*)(sA1 + off);
        }
#pragma unroll
        for (int q = 0; q < 2; ++q)
#pragma unroll
          for (int r = 0; r < 4; ++r) {
            acc0[q][r] = __builtin_amdgcn_mfma_i32_16x16x64_i8(af0[q], bfr[r], acc0[q][r], 0, 0, 0);
            acc1[q][r] = __builtin_amdgcn_mfma_i32_16x16x64_i8(af1[q], bfr[r], acc1[q][r], 0, 0, 0);
          }
      }
    }

    int mx0 = 0, mx1 = 0;
#pragma unroll
    for (int q = 0; q < 2; ++q)
#pragma unroll
      for (int r = 0; r < 4; ++r) {
        const int mrow0 = m0 + wm * 32 + q * 16 + ((lane >> 4) << 2);
        const int co = n0 + wn * 64 + r * 16 + (lane & 15);
#pragma unroll
        for (int e = 0; e < 4; ++e) {
          int v0 = acc0[q][r][e], v1 = acc1[q][r][e];
          mx0 = max(mx0, v0 < 0 ? -v0 : v0);
          mx1 = max(mx1, v1 < 0 ? -v1 : v1);
          size_t idx = (size_t)(mrow0 + e) * COUTc + co;
          p0[idx] = (short)v0;
          p1[idx] = (short)v1;
        }
      }
#pragma unroll
    for (int off = 32; off; off >>= 1) {
      mx0 = max(mx0, __shfl_xor(mx0, off));
      mx1 = max(mx1, __shfl_xor(mx1, off));
    }
    __syncthreads();                     // sB scratch reuse barrier (after last ds_read)
    if (lane == 0) { redi[wv] = mx0; redi[wv + 8] = mx1; }
    __syncthreads();
    if (tid == 0) {
      int a = 0, b = 0;
#pragma unroll
      for (int i = 0; i < 8; ++i) { a = max(a, redi[i]); b = max(b, redi[i + 8]); }
      slot0[bid] = a;
      slot1[bid] = b;
    }
  }
  grid.sync();

  // ================= P3: max|val| partials =================
  int g0 = 0, g1 = 0;
  for (int i = 0; i < GRID; ++i) { g0 = max(g0, slot0[i]); g1 = max(g1, slot1[i]); }
  const float sa0 = fmaxf(__fdiv_rn((float)g0, 31.0f), 1e-12f);
  const float sa1 = fmaxf(__fdiv_rn((float)g1, 31.0f), 1e-12f);
  {
    float mv = 0.f;
    const short4* p04 = (const short4*)p0;
    const short4* p14 = (const short4*)p1;
    const int n4 = MD * COUTc / 4;              // 802,816 -> 8 iters
    for (int i = gtid; i < n4; i += GSTRIDE) {
      short4 a = p04[i], b = p14[i];
      mv = fmaxf(mv, fmaxf(fmaxf(fabsf(compute_val(a.x, b.x, sa0, sa1)),
                                 fabsf(compute_val(a.y, b.y, sa0, sa1))),
                           fmaxf(fabsf(compute_val(a.z, b.z, sa0, sa1)),
                                 fabsf(compute_val(a.w, b.w, sa0, sa1)))));
    }
#pragma unroll
    for (int off = 32; off; off >>= 1) mv = fmaxf(mv, __shfl_xor(mv, off));
    if (lane == 0) redf[wv] = mv;
    __syncthreads();
    if (tid == 0) {
      float m = 0.f;
#pragma unroll
      for (int i = 0; i < 8; ++i) m = fmaxf(m, redf[i]);
      slot_v[bid] = m;
    }
  }
  grid.sync();

  // ================= P4: requant + bias + transpose to [n][co][l] =================
  {
    float gv = 0.f;
    for (int i = 0; i < GRID; ++i) gv = fmaxf(gv, slot_v[i]);
    const float so = fmaxf(__fdiv_rn(__fmul_rn(gv, sx), 127.0f), 1e-12f);

    short* t0s = (short*)sA0;                   // [64][66] = 8448 B
    short* t1s = (short*)sA1;
    for (int t = bid; t < (MD / 64) * (COUTc / 64); t += GRID) {   // 784 tiles, 4 per block
      const int m0 = (t % (MD / 64)) * 64, co0 = (t / (MD / 64)) * 64;
      const int trow = tid >> 3, tseg = tid & 7;        // 64 rows x 8 segs
      __syncthreads();
      {
        int4 v0 = *(const int4*)&p0[(size_t)(m0 + trow) * COUTc + co0 + tseg * 8];
        int4 v1 = *(const int4*)&p1[(size_t)(m0 + trow) * COUTc + co0 + tseg * 8];
        const short* s0 = (const short*)&v0;
        const short* s1 = (const short*)&v1;
#pragma unroll
        for (int j = 0; j < 8; ++j) {
          int col = tseg * 8 + j;
          t0s[col * 66 + trow] = s0[j];
          t1s[col * 66 + trow] = s1[j];
        }
      }
      __syncthreads();
      const int lane16 = tid & 15, cgi = tid >> 4;      // cgi 0..31
#pragma unroll
      for (int p = 0; p < 2; ++p) {
        int col = p * 32 + cgi;
        int m4 = lane16 * 4;
        int mg = m0 + m4;
        int nimg = mg / LSP;
        int l = mg - nimg * LSP;            // 64 | 3136: tile never crosses image
        int co = co0 + col;
        float bv = bias[co];
        float4 o;
        float* op = &o.x;
#pragma unroll
        for (int e = 0; e < 4; ++e) {
          float val = compute_val(t0s[col * 66 + m4 + e], t1s[col * 66 + m4 + e], sa0, sa1);
          float u = __fmul_rn(val, sx);
          float r = rintf(__fdiv_rn(u, so));
          r = fminf(127.f, fmaxf(-127.f, r));
          op[e] = __fadd_rn(__fmul_rn(r, so), bv);
        }
        *(float4*)&out[((size_t)nimg * COUTc + co) * LSP + l] = o;
      }
    }
  }
}

extern "C" void kernel_launch(void* const* d_in, const int* in_sizes, int n_in,
                              void* d_out, int out_size, void* d_ws, size_t ws_size,
                              hipStream_t stream) {
  const float* x    = (const float*)d_in[0];
  const float* w    = (const float*)d_in[1];
  const float* bias = (const float*)d_in[2];
  float* out = (float*)d_out;
  char* ws = (char*)d_ws;

  void* args[] = {(void*)&x, (void*)&w, (void*)&bias, (void*)&out, (void*)&ws};
  hipLaunchCooperativeKernel((const void*)k_fused, dim3(GRID), dim3(NTHR), args, 0, stream);
}

// Round 7
// 86.677 us; speedup vs baseline: 2.3164x; 2.3164x over previous
//
#include <hip/hip_runtime.h>
#include <hip/hip_bf16.h>

typedef int i32x4 __attribute__((ext_vector_type(4)));

namespace {
constexpr int NB = 4, CINc = 256, Hc = 56, Wc = 56, COUTc = 256;
constexpr int LSP = 56 * 56;           // 3136 output pixels per image
constexpr int MD  = NB * LSP;          // 12544 GEMM rows
constexpr int KT  = 2304;              // 256*9
constexpr int YP = 58, XP = 58;        // padded spatial

// workspace layout
constexpr size_t OFF_A0 = 8192;                             // after slot arrays
constexpr size_t SZ_ACL = (size_t)NB * YP * XP * 256;       // 3,444,736 (i8)
constexpr size_t OFF_A1 = OFF_A0 + SZ_ACL;
constexpr size_t OFF_BW = OFF_A1 + SZ_ACL;
constexpr size_t SZ_BW  = (size_t)COUTc * KT;               // 589,824 (i8)
constexpr size_t OFF_P0 = OFF_BW + SZ_BW;
constexpr size_t SZ_P   = (size_t)MD * COUTc * 2;           // 6,422,528 (i16)
constexpr size_t OFF_P1 = OFF_P0 + SZ_P;                    // end ~20.3 MB
} // namespace

__device__ __forceinline__ float wave_max_f(const float* __restrict__ s, int n) {
  float m = 0.f;
  for (int i = (threadIdx.x & 63); i < n; i += 64) m = fmaxf(m, s[i]);
#pragma unroll
  for (int off = 32; off; off >>= 1) m = fmaxf(m, __shfl_xor(m, off));
  return m;
}
__device__ __forceinline__ int wave_max_i(const int* __restrict__ s, int n) {
  int m = 0;
  for (int i = (threadIdx.x & 63); i < n; i += 64) m = max(m, s[i]);
#pragma unroll
  for (int off = 32; off; off >>= 1) m = max(m, __shfl_xor(m, off));
  return m;
}

// ============ K1: zero a0/a1 + absmax(x) partials + binarize/reorder W ============
__global__ __launch_bounds__(256) void k_prep(const float* __restrict__ x,
                                              const float* __restrict__ w,
                                              char* __restrict__ ws) {
  __shared__ char sW[KT];
  __shared__ float redf[4];
  float* slot_a = (float*)ws;
  char* a01 = ws + OFF_A0;
  char* bw  = ws + OFF_BW;
  const int tid = threadIdx.x, bid = blockIdx.x;
  const int gtid = bid * 256 + tid;                 // 65,536 threads

  // zero a0+a1 (contiguous 2*SZ_ACL)
  {
    int4* pz = (int4*)a01;
    const int nz = (int)(2 * SZ_ACL / 16);          // 430,592
    for (int i = gtid; i < nz; i += 256 * 256) pz[i] = int4{0, 0, 0, 0};
  }
  // binarize + reorder weights for co = bid
  {
    const float* src = w + (size_t)bid * KT;
    for (int t = tid; t < KT; t += 256)             // t = cin*9 + s
      sW[t] = src[t] >= 0.f ? (char)1 : (char)-1;
    __syncthreads();
    char4* dst4 = (char4*)(bw + (size_t)bid * KT);
    for (int j4 = tid; j4 < KT / 4; j4 += 256) {
      char4 v; char* vp = (char*)&v;
#pragma unroll
      for (int e = 0; e < 4; ++e) {
        int j = j4 * 4 + e;                         // j = s*256 + cin
        vp[e] = sW[(j & 255) * 9 + (j >> 8)];
      }
      dst4[j4] = v;
    }
  }
  // absmax(x) partial -> slot_a[bid]
  {
    float mx = 0.f;
    const float4* x4 = (const float4*)x;
    const int n4 = NB * CINc * Hc * Wc / 4;         // 802,816
    for (int i = gtid; i < n4; i += 256 * 256) {
      float4 v = x4[i];
      mx = fmaxf(mx, fmaxf(fmaxf(fabsf(v.x), fabsf(v.y)), fmaxf(fabsf(v.z), fabsf(v.w))));
    }
#pragma unroll
    for (int off = 32; off; off >>= 1) mx = fmaxf(mx, __shfl_xor(mx, off));
    if ((tid & 63) == 0) redf[tid >> 6] = mx;
    __syncthreads();
    if (tid == 0) slot_a[bid] = fmaxf(fmaxf(redf[0], redf[1]), fmaxf(redf[2], redf[3]));
  }
}

// ============ K2: quantize -> i8 DAC slices, channels-last padded ============
__global__ __launch_bounds__(1024) void k_quant(const float* __restrict__ x,
                                                char* __restrict__ ws) {
  __shared__ char t0[56 * 256];
  __shared__ char t1[56 * 256];
  const float* slot_a = (const float*)ws;
  char* a0 = ws + OFF_A0;
  char* a1 = ws + OFF_A1;
  const int n = blockIdx.x / Hc, h = blockIdx.x % Hc;
  const float gmax = wave_max_f(slot_a, 256);
  const float sx = fmaxf(__fdiv_rn(gmax, 7.0f), 1e-12f);
  const int c = threadIdx.x & 255, wq = threadIdx.x >> 8;
  const float2* src = (const float2*)(x + (((size_t)n * CINc + c) * Hc + h) * Wc + wq * 14);
#pragma unroll
  for (int j = 0; j < 7; ++j) {
    float2 v = src[j];
    float arr[2] = {v.x, v.y};
#pragma unroll
    for (int e = 0; e < 2; ++e) {
      float qf = rintf(__fdiv_rn(arr[e], sx));
      qf = fminf(7.f, fmaxf(-7.f, qf));
      int qi = (int)qf;
      int mag = qi < 0 ? -qi : qi;
      int s0 = mag & 3, s1 = mag >> 2;
      if (qi < 0) { s0 = -s0; s1 = -s1; }
      int ww = wq * 14 + j * 2 + e;
      t0[ww * 256 + c] = (char)s0;
      t1[ww * 256 + c] = (char)s1;
    }
  }
  __syncthreads();
  {
    int idx = threadIdx.x;              // 56*16 = 896 int4 slots per array
    if (idx < 896) {
      int wr = idx >> 4, c16 = (idx & 15) << 4;
      int4 v0 = *(const int4*)&t0[wr * 256 + c16];
      int4 v1 = *(const int4*)&t1[wr * 256 + c16];
      size_t dst = (((size_t)n * YP + (h + 1)) * XP + (wr + 1)) * 256 + c16;
      *(int4*)&a0[dst] = v0;
      *(int4*)&a1[dst] = v1;
    }
  }
}

// ============ K3: dual i8 GEMM, 128x128 tile, dbuf LDS + raw-barrier pipeline ============
__global__ __launch_bounds__(512, 1) void k_gemm(char* __restrict__ ws) {
  __shared__ __align__(16) char sA0[2 * 16384];
  __shared__ __align__(16) char sA1[2 * 16384];
  __shared__ __align__(16) char sB[2 * 16384];
  __shared__ int red[16];

  const char* a0cl = ws + OFF_A0;
  const char* a1cl = ws + OFF_A1;
  const char* bw   = ws + OFF_BW;
  short* p0 = (short*)(ws + OFF_P0);
  short* p1 = (short*)(ws + OFF_P1);
  int* slot0 = (int*)(ws + 1024);
  int* slot1 = (int*)(ws + 2048);

  const int tid = threadIdx.x;
  const int lane = tid & 63, wid = tid >> 6;
  const int wm = wid >> 1, wn = wid & 1;          // 4x2 waves, 32x64 each

  // bijective XCD swizzle for 196 blocks
  const int bid = blockIdx.x;
  const int xcd = bid & 7;
  const int wg = (xcd < 4 ? xcd * 25 : 100 + (xcd - 4) * 24) + (bid >> 3);
  const int nblk = wg & 1, mblk = wg >> 1;
  const int m0 = mblk * 128, n0 = nblk * 128;

  i32x4 acc0[2][4] = {};
  i32x4 acc1[2][4] = {};

  const int trow = tid >> 3;          // 0..63
  const int cb = (tid & 7) * 16;      // 16B seg within 128B row

  int rn[2], roh[2], rww[2], dstb[2];
#pragma unroll
  for (int p = 0; p < 2; ++p) {
    int m = m0 + p * 64 + trow;
    rn[p] = m / LSP; int l = m - rn[p] * LSP;
    roh[p] = l / 56; rww[p] = l - roh[p] * 56;
    int r = p * 64 + trow;
    dstb[p] = r * 128 + (cb ^ ((r & 7) << 4));
  }

  int4 ra0[2], ra1[2], rb[2];
  auto LOAD = [&](int kb) {
    const int slab = kb >> 1;
    const int kh = slab / 3, kw = slab - (slab / 3) * 3;
    const int c0 = (kb & 1) << 7;
#pragma unroll
    for (int p = 0; p < 2; ++p) {
      size_t ga = (((size_t)rn[p] * YP + (roh[p] + kh)) * XP + (rww[p] + kw)) * 256 + c0 + cb;
      ra0[p] = *(const int4*)(a0cl + ga);
      ra1[p] = *(const int4*)(a1cl + ga);
      size_t gb = (size_t)(n0 + p * 64 + trow) * KT + kb * 128 + cb;
      rb[p] = *(const int4*)(bw + gb);
    }
  };
  auto WRITE = [&](int buf) {
#pragma unroll
    for (int p = 0; p < 2; ++p) {
      *(int4*)(sA0 + buf * 16384 + dstb[p]) = ra0[p];
      *(int4*)(sA1 + buf * 16384 + dstb[p]) = ra1[p];
      *(int4*)(sB + buf * 16384 + dstb[p]) = rb[p];
    }
  };
  auto ITER = [&](int kb, int cur) {
    const char* bA0 = sA0 + cur * 16384;
    const char* bA1 = sA1 + cur * 16384;
    const char* bB  = sB + cur * 16384;
#pragma unroll
    for (int ks = 0; ks < 2; ++ks) {
      const int kbyte = ks * 64 + ((lane >> 4) << 4);
      i32x4 bfr[4], af0[2], af1[2];
#pragma unroll
      for (int r = 0; r < 4; ++r) {
        int rr = wn * 64 + r * 16 + (lane & 15);
        bfr[r] = *(const i32x4*)(bB + rr * 128 + (kbyte ^ ((rr & 7) << 4)));
      }
#pragma unroll
      for (int q = 0; q < 2; ++q) {
        int rr = wm * 32 + q * 16 + (lane & 15);
        int off = rr * 128 + (kbyte ^ ((rr & 7) << 4));
        af0[q] = *(const i32x4*)(bA0 + off);
        af1[q] = *(const i32x4*)(bA1 + off);
      }
#pragma unroll
      for (int q = 0; q < 2; ++q)
#pragma unroll
        for (int r = 0; r < 4; ++r) {
          acc0[q][r] = __builtin_amdgcn_mfma_i32_16x16x64_i8(af0[q], bfr[r], acc0[q][r], 0, 0, 0);
          acc1[q][r] = __builtin_amdgcn_mfma_i32_16x16x64_i8(af1[q], bfr[r], acc1[q][r], 0, 0, 0);
        }
    }
    if (kb < 17) {
      WRITE(cur ^ 1);                   // compiler waits vmcnt for reg deps only
      if (kb < 16) LOAD(kb + 2);        // stays in flight across the barrier
    }
    asm volatile("s_waitcnt lgkmcnt(0)" ::: "memory");   // my ds ops done; vmem NOT drained
    __builtin_amdgcn_s_barrier();
    asm volatile("" ::: "memory");
  };

  // prologue
  LOAD(0);
  WRITE(0);
  LOAD(1);
  asm volatile("s_waitcnt lgkmcnt(0)" ::: "memory");
  __builtin_amdgcn_s_barrier();
  asm volatile("" ::: "memory");

#pragma unroll 1
  for (int kbb = 0; kbb < 9; ++kbb) {
    ITER(2 * kbb, 0);
    ITER(2 * kbb + 1, 1);
  }

  // epilogue: store p0/p1 + per-block max slots
  int mx0 = 0, mx1 = 0;
#pragma unroll
  for (int q = 0; q < 2; ++q)
#pragma unroll
    for (int r = 0; r < 4; ++r) {
      const int mrow0 = m0 + wm * 32 + q * 16 + ((lane >> 4) << 2);
      const int co = n0 + wn * 64 + r * 16 + (lane & 15);
#pragma unroll
      for (int e = 0; e < 4; ++e) {
        int v0 = acc0[q][r][e], v1 = acc1[q][r][e];
        mx0 = max(mx0, v0 < 0 ? -v0 : v0);
        mx1 = max(mx1, v1 < 0 ? -v1 : v1);
        size_t idx = (size_t)(mrow0 + e) * COUTc + co;
        p0[idx] = (short)v0;
        p1[idx] = (short)v1;
      }
    }
#pragma unroll
  for (int off = 32; off; off >>= 1) {
    mx0 = max(mx0, __shfl_xor(mx0, off));
    mx1 = max(mx1, __shfl_xor(mx1, off));
  }
  if (lane == 0) { red[wid] = mx0; red[wid + 8] = mx1; }
  __syncthreads();
  if (tid == 0) {
    int a = 0, b = 0;
#pragma unroll
    for (int i = 0; i < 8; ++i) { a = max(a, red[i]); b = max(b, red[i + 8]); }
    slot0[bid] = a;
    slot1[bid] = b;
  }
}

__device__ __forceinline__ float compute_val(int a, int b, float sa0, float sa1) {
  float q0 = rintf(__fdiv_rn((float)a, sa0));
  q0 = fminf(31.f, fmaxf(-31.f, q0));
  float q1 = rintf(__fdiv_rn((float)b, sa1));
  q1 = fminf(31.f, fmaxf(-31.f, q1));
  float acc = __fadd_rn(__fmul_rn(q0, sa0), __fmul_rn(__fmul_rn(q1, sa1), 4.0f));
  float pe = (float)(a + 4 * b);
  return __fadd_rn(pe, __fsub_rn(acc, pe));
}

// ============ K4: max|val| partials ============
__global__ __launch_bounds__(256) void k_maxval(char* __restrict__ ws) {
  __shared__ float redf[4];
  const short* p0 = (const short*)(ws + OFF_P0);
  const short* p1 = (const short*)(ws + OFF_P1);
  const int* slot0 = (const int*)(ws + 1024);
  const int* slot1 = (const int*)(ws + 2048);
  float* slot_v = (float*)(ws + 3072);

  const float sa0 = fmaxf(__fdiv_rn((float)wave_max_i(slot0, 196), 31.0f), 1e-12f);
  const float sa1 = fmaxf(__fdiv_rn((float)wave_max_i(slot1, 196), 31.0f), 1e-12f);

  float mv = 0.f;
  const short4* p04 = (const short4*)p0;
  const short4* p14 = (const short4*)p1;
  const int n4 = MD * COUTc / 4;                    // 802,816
  for (int i = blockIdx.x * 256 + threadIdx.x; i < n4; i += 512 * 256) {
    short4 a = p04[i], b = p14[i];
    mv = fmaxf(mv, fmaxf(fmaxf(fabsf(compute_val(a.x, b.x, sa0, sa1)),
                               fabsf(compute_val(a.y, b.y, sa0, sa1))),
                         fmaxf(fabsf(compute_val(a.z, b.z, sa0, sa1)),
                               fabsf(compute_val(a.w, b.w, sa0, sa1)))));
  }
#pragma unroll
  for (int off = 32; off; off >>= 1) mv = fmaxf(mv, __shfl_xor(mv, off));
  if ((threadIdx.x & 63) == 0) redf[threadIdx.x >> 6] = mv;
  __syncthreads();
  if (threadIdx.x == 0)
    slot_v[blockIdx.x] = fmaxf(fmaxf(redf[0], redf[1]), fmaxf(redf[2], redf[3]));
}

// ============ K5: requant + bias + transpose to [n][co][l] ============
__global__ __launch_bounds__(256) void k_final(const float* __restrict__ bias,
                                               float* __restrict__ out,
                                               char* __restrict__ ws) {
  __shared__ short t0[64 * 66];
  __shared__ short t1[64 * 66];
  const short* p0 = (const short*)(ws + OFF_P0);
  const short* p1 = (const short*)(ws + OFF_P1);
  const float* slot_a = (const float*)ws;
  const int* slot0 = (const int*)(ws + 1024);
  const int* slot1 = (const int*)(ws + 2048);
  const float* slot_v = (const float*)(ws + 3072);

  const float sx  = fmaxf(__fdiv_rn(wave_max_f(slot_a, 256), 7.0f), 1e-12f);
  const float sa0 = fmaxf(__fdiv_rn((float)wave_max_i(slot0, 196), 31.0f), 1e-12f);
  const float sa1 = fmaxf(__fdiv_rn((float)wave_max_i(slot1, 196), 31.0f), 1e-12f);
  const float so  = fmaxf(__fdiv_rn(__fmul_rn(wave_max_f(slot_v, 512), sx), 127.0f), 1e-12f);

  const int m0 = blockIdx.x * 64, co0 = blockIdx.y * 64;
  const int trow = threadIdx.x >> 3, tseg = threadIdx.x & 7;
#pragma unroll
  for (int p = 0; p < 2; ++p) {
    int ml = p * 32 + trow;
    int4 v0 = *(const int4*)&p0[(size_t)(m0 + ml) * COUTc + co0 + tseg * 8];
    int4 v1 = *(const int4*)&p1[(size_t)(m0 + ml) * COUTc + co0 + tseg * 8];
    const short* s0 = (const short*)&v0;
    const short* s1 = (const short*)&v1;
#pragma unroll
    for (int j = 0; j < 8; ++j) {
      int col = tseg * 8 + j;
      t0[col * 66 + ml] = s0[j];
      t1[col * 66 + ml] = s1[j];
    }
  }
  __syncthreads();
  const int lane16 = threadIdx.x & 15, cg = threadIdx.x >> 4;
#pragma unroll
  for (int p = 0; p < 4; ++p) {
    int col = p * 16 + cg;
    int m4 = lane16 * 4;
    int mg = m0 + m4;
    int nimg = mg / LSP;
    int l = mg - nimg * LSP;
    int co = co0 + col;
    float bv = bias[co];
    float4 o;
    float* op = &o.x;
#pragma unroll
    for (int e = 0; e < 4; ++e) {
      float val = compute_val(t0[col * 66 + m4 + e], t1[col * 66 + m4 + e], sa0, sa1);
      float u = __fmul_rn(val, sx);
      float r = rintf(__fdiv_rn(u, so));
      r = fminf(127.f, fmaxf(-127.f, r));
      op[e] = __fadd_rn(__fmul_rn(r, so), bv);
    }
    *(float4*)&out[((size_t)nimg * COUTc + co) * LSP + l] = o;
  }
}

extern "C" void kernel_launch(void* const* d_in, const int* in_sizes, int n_in,
                              void* d_out, int out_size, void* d_ws, size_t ws_size,
                              hipStream_t stream) {
  const float* x    = (const float*)d_in[0];
  const float* w    = (const float*)d_in[1];
  const float* bias = (const float*)d_in[2];
  float* out = (float*)d_out;
  char* ws = (char*)d_ws;

  k_prep<<<256, 256, 0, stream>>>(x, w, ws);
  k_quant<<<NB * Hc, 1024, 0, stream>>>(x, ws);
  k_gemm<<<196, 512, 0, stream>>>(ws);
  k_maxval<<<512, 256, 0, stream>>>(ws);
  k_final<<<dim3(MD / 64, COUTc / 64), 256, 0, stream>>>(bias, out, ws);
}

// Round 8
// 71.577 us; speedup vs baseline: 2.8051x; 1.2110x over previous
//
#include <hip/hip_runtime.h>
#include <hip/hip_bf16.h>

typedef int i32x4 __attribute__((ext_vector_type(4)));

#define GLL16(gp, lp)                                                          \
  __builtin_amdgcn_global_load_lds(                                            \
      (const __attribute__((address_space(1))) void*)(gp),                     \
      (__attribute__((address_space(3))) void*)(lp), 16, 0, 0)

namespace {
constexpr int NB = 4, CINc = 256, Hc = 56, Wc = 56, COUTc = 256;
constexpr int LSP = 56 * 56;           // 3136 output pixels per image
constexpr int MD  = NB * LSP;          // 12544 GEMM rows
constexpr int KT  = 2304;              // 256*9
constexpr int YP = 58, XP = 58;        // padded spatial

// workspace layout
constexpr size_t OFF_A0 = 8192;                             // after slot arrays
constexpr size_t SZ_ACL = (size_t)NB * YP * XP * 256;       // 3,444,736 (i8)
constexpr size_t OFF_A1 = OFF_A0 + SZ_ACL;
constexpr size_t OFF_BW = OFF_A1 + SZ_ACL;
constexpr size_t SZ_BW  = (size_t)COUTc * KT;               // 589,824 (i8)
constexpr size_t OFF_P0 = OFF_BW + SZ_BW;
constexpr size_t SZ_P   = (size_t)MD * COUTc * 2;           // 6,422,528 (i16)
constexpr size_t OFF_P1 = OFF_P0 + SZ_P;                    // end ~20.3 MB
} // namespace

__device__ __forceinline__ float wave_max_f(const float* __restrict__ s, int n) {
  float m = 0.f;
  for (int i = (threadIdx.x & 63); i < n; i += 64) m = fmaxf(m, s[i]);
#pragma unroll
  for (int off = 32; off; off >>= 1) m = fmaxf(m, __shfl_xor(m, off));
  return m;
}
__device__ __forceinline__ int wave_max_i(const int* __restrict__ s, int n) {
  int m = 0;
  for (int i = (threadIdx.x & 63); i < n; i += 64) m = max(m, s[i]);
#pragma unroll
  for (int off = 32; off; off >>= 1) m = max(m, __shfl_xor(m, off));
  return m;
}

// ============ K1: zero a0/a1 + absmax(x) partials + binarize/reorder W ============
__global__ __launch_bounds__(256) void k_prep(const float* __restrict__ x,
                                              const float* __restrict__ w,
                                              char* __restrict__ ws) {
  __shared__ char sW[KT];
  __shared__ float redf[4];
  float* slot_a = (float*)ws;
  char* a01 = ws + OFF_A0;
  char* bw  = ws + OFF_BW;
  const int tid = threadIdx.x, bid = blockIdx.x;
  const int gtid = bid * 256 + tid;                 // 65,536 threads

  {
    int4* pz = (int4*)a01;
    const int nz = (int)(2 * SZ_ACL / 16);          // 430,592
    for (int i = gtid; i < nz; i += 256 * 256) pz[i] = int4{0, 0, 0, 0};
  }
  {
    const float* src = w + (size_t)bid * KT;
    for (int t = tid; t < KT; t += 256)             // t = cin*9 + s
      sW[t] = src[t] >= 0.f ? (char)1 : (char)-1;
    __syncthreads();
    char4* dst4 = (char4*)(bw + (size_t)bid * KT);
    for (int j4 = tid; j4 < KT / 4; j4 += 256) {
      char4 v; char* vp = (char*)&v;
#pragma unroll
      for (int e = 0; e < 4; ++e) {
        int j = j4 * 4 + e;                         // j = s*256 + cin
        vp[e] = sW[(j & 255) * 9 + (j >> 8)];
      }
      dst4[j4] = v;
    }
  }
  {
    float mx = 0.f;
    const float4* x4 = (const float4*)x;
    const int n4 = NB * CINc * Hc * Wc / 4;         // 802,816
    for (int i = gtid; i < n4; i += 256 * 256) {
      float4 v = x4[i];
      mx = fmaxf(mx, fmaxf(fmaxf(fabsf(v.x), fabsf(v.y)), fmaxf(fabsf(v.z), fabsf(v.w))));
    }
#pragma unroll
    for (int off = 32; off; off >>= 1) mx = fmaxf(mx, __shfl_xor(mx, off));
    if ((tid & 63) == 0) redf[tid >> 6] = mx;
    __syncthreads();
    if (tid == 0) slot_a[bid] = fmaxf(fmaxf(redf[0], redf[1]), fmaxf(redf[2], redf[3]));
  }
}

// ============ K2: quantize -> i8 DAC slices, channels-last padded ============
__global__ __launch_bounds__(1024) void k_quant(const float* __restrict__ x,
                                                char* __restrict__ ws) {
  __shared__ char t0[56 * 256];
  __shared__ char t1[56 * 256];
  const float* slot_a = (const float*)ws;
  char* a0 = ws + OFF_A0;
  char* a1 = ws + OFF_A1;
  const int n = blockIdx.x / Hc, h = blockIdx.x % Hc;
  const float gmax = wave_max_f(slot_a, 256);
  const float sx = fmaxf(__fdiv_rn(gmax, 7.0f), 1e-12f);
  const int c = threadIdx.x & 255, wq = threadIdx.x >> 8;
  const float2* src = (const float2*)(x + (((size_t)n * CINc + c) * Hc + h) * Wc + wq * 14);
#pragma unroll
  for (int j = 0; j < 7; ++j) {
    float2 v = src[j];
    float arr[2] = {v.x, v.y};
#pragma unroll
    for (int e = 0; e < 2; ++e) {
      float qf = rintf(__fdiv_rn(arr[e], sx));
      qf = fminf(7.f, fmaxf(-7.f, qf));
      int qi = (int)qf;
      int mag = qi < 0 ? -qi : qi;
      int s0 = mag & 3, s1 = mag >> 2;
      if (qi < 0) { s0 = -s0; s1 = -s1; }
      int ww = wq * 14 + j * 2 + e;
      t0[ww * 256 + c] = (char)s0;
      t1[ww * 256 + c] = (char)s1;
    }
  }
  __syncthreads();
  {
    int idx = threadIdx.x;              // 56*16 = 896 int4 slots per array
    if (idx < 896) {
      int wr = idx >> 4, c16 = (idx & 15) << 4;
      int4 v0 = *(const int4*)&t0[wr * 256 + c16];
      int4 v1 = *(const int4*)&t1[wr * 256 + c16];
      size_t dst = (((size_t)n * YP + (h + 1)) * XP + (wr + 1)) * 256 + c16;
      *(int4*)&a0[dst] = v0;
      *(int4*)&a1[dst] = v1;
    }
  }
}

// ============ K3: dual i8 GEMM, 128x128 tile, dbuf LDS + global_load_lds ============
// T3-minimum 2-phase: STAGE(next buf via gload_lds) -> compute(cur) -> syncthreads.
// LDS dest is linear (wave-uniform base + lane*16); the XOR swizzle is applied to
// the per-lane GLOBAL source address and again on the ds_read side (rule #21).
__global__ __launch_bounds__(512, 1) void k_gemm(char* __restrict__ ws) {
  __shared__ __align__(16) char sA0[2 * 16384];
  __shared__ __align__(16) char sA1[2 * 16384];
  __shared__ __align__(16) char sB[2 * 16384];
  __shared__ int red[16];

  const char* a0cl = ws + OFF_A0;
  const char* a1cl = ws + OFF_A1;
  const char* bw   = ws + OFF_BW;
  short* p0 = (short*)(ws + OFF_P0);
  short* p1 = (short*)(ws + OFF_P1);
  int* slot0 = (int*)(ws + 1024);
  int* slot1 = (int*)(ws + 2048);

  const int tid = threadIdx.x;
  const int lane = tid & 63, wid = tid >> 6;
  const int wm = wid >> 1, wn = wid & 1;          // 4x2 waves, 32x64 each

  // bijective XCD swizzle for 196 blocks
  const int bid = blockIdx.x;
  const int xcd = bid & 7;
  const int wg = (xcd < 4 ? xcd * 25 : 100 + (xcd - 4) * 24) + (bid >> 3);
  const int nblk = wg & 1, mblk = wg >> 1;
  const int m0 = mblk * 128, n0 = nblk * 128;

  i32x4 acc0[2][4] = {};
  i32x4 acc1[2][4] = {};

  const int trow = tid >> 3;                       // 0..63 (= wid*8 + (lane>>3))
  // pre-swizzled source byte-offset within the 128B row segment:
  const int cbs = (((tid & 7) << 4) ^ ((trow & 7) << 4));

  int rn[2], roh[2], rww[2];
#pragma unroll
  for (int p = 0; p < 2; ++p) {
    int m = m0 + p * 64 + trow;
    rn[p] = m / LSP; int l = m - rn[p] * LSP;
    roh[p] = l / 56; rww[p] = l - roh[p] * 56;
  }
  // wave-uniform LDS byte base for this wave's 8-row group (per p half)
  const int lbase0 = (0 * 64 + wid * 8) * 128;
  const int lbase1 = (1 * 64 + wid * 8) * 128;

  auto STAGE = [&](int kb, int buf) {
    const int slab = kb >> 1;
    const int kh = slab / 3, kw = slab - (slab / 3) * 3;
    const int c0 = (kb & 1) << 7;
    const int bo = buf * 16384;
    {
      size_t ga = (((size_t)rn[0] * YP + (roh[0] + kh)) * XP + (rww[0] + kw)) * 256 + c0 + cbs;
      GLL16(a0cl + ga, sA0 + bo + lbase0);
      GLL16(a1cl + ga, sA1 + bo + lbase0);
      size_t gb = (size_t)(n0 + 0 * 64 + trow) * KT + kb * 128 + cbs;
      GLL16(bw + gb, sB + bo + lbase0);
    }
    {
      size_t ga = (((size_t)rn[1] * YP + (roh[1] + kh)) * XP + (rww[1] + kw)) * 256 + c0 + cbs;
      GLL16(a0cl + ga, sA0 + bo + lbase1);
      GLL16(a1cl + ga, sA1 + bo + lbase1);
      size_t gb = (size_t)(n0 + 1 * 64 + trow) * KT + kb * 128 + cbs;
      GLL16(bw + gb, sB + bo + lbase1);
    }
  };

  auto COMPUTE = [&](int buf) {
    const char* bA0 = sA0 + buf * 16384;
    const char* bA1 = sA1 + buf * 16384;
    const char* bB  = sB + buf * 16384;
#pragma unroll
    for (int ks = 0; ks < 2; ++ks) {
      const int kbyte = ks * 64 + ((lane >> 4) << 4);
      i32x4 bfr[4], af0[2], af1[2];
#pragma unroll
      for (int r = 0; r < 4; ++r) {
        int rr = wn * 64 + r * 16 + (lane & 15);
        bfr[r] = *(const i32x4*)(bB + rr * 128 + (kbyte ^ ((rr & 7) << 4)));
      }
#pragma unroll
      for (int q = 0; q < 2; ++q) {
        int rr = wm * 32 + q * 16 + (lane & 15);
        int off = rr * 128 + (kbyte ^ ((rr & 7) << 4));
        af0[q] = *(const i32x4*)(bA0 + off);
        af1[q] = *(const i32x4*)(bA1 + off);
      }
#pragma unroll
      for (int q = 0; q < 2; ++q)
#pragma unroll
        for (int r = 0; r < 4; ++r) {
          acc0[q][r] = __builtin_amdgcn_mfma_i32_16x16x64_i8(af0[q], bfr[r], acc0[q][r], 0, 0, 0);
          acc1[q][r] = __builtin_amdgcn_mfma_i32_16x16x64_i8(af1[q], bfr[r], acc1[q][r], 0, 0, 0);
        }
    }
  };

  // prologue: fill buf0
  STAGE(0, 0);
  __syncthreads();                       // vmcnt(0) drain -> buf0 ready

  int buf = 0;
#pragma unroll 1
  for (int kb = 0; kb < KT / 128; ++kb) {          // 18 steps
    if (kb < 17) STAGE(kb + 1, buf ^ 1);           // issue-early: latency hides under compute
    COMPUTE(buf);
    __syncthreads();                               // drains staged loads; guards buf reuse
    buf ^= 1;
  }

  // epilogue: store p0/p1 + per-block max slots
  int mx0 = 0, mx1 = 0;
#pragma unroll
  for (int q = 0; q < 2; ++q)
#pragma unroll
    for (int r = 0; r < 4; ++r) {
      const int mrow0 = m0 + wm * 32 + q * 16 + ((lane >> 4) << 2);
      const int co = n0 + wn * 64 + r * 16 + (lane & 15);
#pragma unroll
      for (int e = 0; e < 4; ++e) {
        int v0 = acc0[q][r][e], v1 = acc1[q][r][e];
        mx0 = max(mx0, v0 < 0 ? -v0 : v0);
        mx1 = max(mx1, v1 < 0 ? -v1 : v1);
        size_t idx = (size_t)(mrow0 + e) * COUTc + co;
        p0[idx] = (short)v0;
        p1[idx] = (short)v1;
      }
    }
#pragma unroll
  for (int off = 32; off; off >>= 1) {
    mx0 = max(mx0, __shfl_xor(mx0, off));
    mx1 = max(mx1, __shfl_xor(mx1, off));
  }
  if (lane == 0) { red[wid] = mx0; red[wid + 8] = mx1; }
  __syncthreads();
  if (tid == 0) {
    int a = 0, b = 0;
#pragma unroll
    for (int i = 0; i < 8; ++i) { a = max(a, red[i]); b = max(b, red[i + 8]); }
    slot0[bid] = a;
    slot1[bid] = b;
  }
}

__device__ __forceinline__ float compute_val(int a, int b, float sa0, float sa1) {
  float q0 = rintf(__fdiv_rn((float)a, sa0));
  q0 = fminf(31.f, fmaxf(-31.f, q0));
  float q1 = rintf(__fdiv_rn((float)b, sa1));
  q1 = fminf(31.f, fmaxf(-31.f, q1));
  float acc = __fadd_rn(__fmul_rn(q0, sa0), __fmul_rn(__fmul_rn(q1, sa1), 4.0f));
  float pe = (float)(a + 4 * b);
  return __fadd_rn(pe, __fsub_rn(acc, pe));
}

// ============ K4: max|val| partials ============
__global__ __launch_bounds__(256) void k_maxval(char* __restrict__ ws) {
  __shared__ float redf[4];
  const short* p0 = (const short*)(ws + OFF_P0);
  const short* p1 = (const short*)(ws + OFF_P1);
  const int* slot0 = (const int*)(ws + 1024);
  const int* slot1 = (const int*)(ws + 2048);
  float* slot_v = (float*)(ws + 3072);

  const float sa0 = fmaxf(__fdiv_rn((float)wave_max_i(slot0, 196), 31.0f), 1e-12f);
  const float sa1 = fmaxf(__fdiv_rn((float)wave_max_i(slot1, 196), 31.0f), 1e-12f);

  float mv = 0.f;
  const short4* p04 = (const short4*)p0;
  const short4* p14 = (const short4*)p1;
  const int n4 = MD * COUTc / 4;                    // 802,816
  for (int i = blockIdx.x * 256 + threadIdx.x; i < n4; i += 512 * 256) {
    short4 a = p04[i], b = p14[i];
    mv = fmaxf(mv, fmaxf(fmaxf(fabsf(compute_val(a.x, b.x, sa0, sa1)),
                               fabsf(compute_val(a.y, b.y, sa0, sa1))),
                         fmaxf(fabsf(compute_val(a.z, b.z, sa0, sa1)),
                               fabsf(compute_val(a.w, b.w, sa0, sa1)))));
  }
#pragma unroll
  for (int off = 32; off; off >>= 1) mv = fmaxf(mv, __shfl_xor(mv, off));
  if ((threadIdx.x & 63) == 0) redf[threadIdx.x >> 6] = mv;
  __syncthreads();
  if (threadIdx.x == 0)
    slot_v[blockIdx.x] = fmaxf(fmaxf(redf[0], redf[1]), fmaxf(redf[2], redf[3]));
}

// ============ K5: requant + bias + transpose to [n][co][l] ============
__global__ __launch_bounds__(256) void k_final(const float* __restrict__ bias,
                                               float* __restrict__ out,
                                               char* __restrict__ ws) {
  __shared__ short t0[64 * 66];
  __shared__ short t1[64 * 66];
  const short* p0 = (const short*)(ws + OFF_P0);
  const short* p1 = (const short*)(ws + OFF_P1);
  const float* slot_a = (const float*)ws;
  const int* slot0 = (const int*)(ws + 1024);
  const int* slot1 = (const int*)(ws + 2048);
  const float* slot_v = (const float*)(ws + 3072);

  const float sx  = fmaxf(__fdiv_rn(wave_max_f(slot_a, 256), 7.0f), 1e-12f);
  const float sa0 = fmaxf(__fdiv_rn((float)wave_max_i(slot0, 196), 31.0f), 1e-12f);
  const float sa1 = fmaxf(__fdiv_rn((float)wave_max_i(slot1, 196), 31.0f), 1e-12f);
  const float so  = fmaxf(__fdiv_rn(__fmul_rn(wave_max_f(slot_v, 512), sx), 127.0f), 1e-12f);

  const int m0 = blockIdx.x * 64, co0 = blockIdx.y * 64;
  const int trow = threadIdx.x >> 3, tseg = threadIdx.x & 7;
#pragma unroll
  for (int p = 0; p < 2; ++p) {
    int ml = p * 32 + trow;
    int4 v0 = *(const int4*)&p0[(size_t)(m0 + ml) * COUTc + co0 + tseg * 8];
    int4 v1 = *(const int4*)&p1[(size_t)(m0 + ml) * COUTc + co0 + tseg * 8];
    const short* s0 = (const short*)&v0;
    const short* s1 = (const short*)&v1;
#pragma unroll
    for (int j = 0; j < 8; ++j) {
      int col = tseg * 8 + j;
      t0[col * 66 + ml] = s0[j];
      t1[col * 66 + ml] = s1[j];
    }
  }
  __syncthreads();
  const int lane16 = threadIdx.x & 15, cg = threadIdx.x >> 4;
#pragma unroll
  for (int p = 0; p < 4; ++p) {
    int col = p * 16 + cg;
    int m4 = lane16 * 4;
    int mg = m0 + m4;
    int nimg = mg / LSP;
    int l = mg - nimg * LSP;
    int co = co0 + col;
    float bv = bias[co];
    float4 o;
    float* op = &o.x;
#pragma unroll
    for (int e = 0; e < 4; ++e) {
      float val = compute_val(t0[col * 66 + m4 + e], t1[col * 66 + m4 + e], sa0, sa1);
      float u = __fmul_rn(val, sx);
      float r = rintf(__fdiv_rn(u, so));
      r = fminf(127.f, fmaxf(-127.f, r));
      op[e] = __fadd_rn(__fmul_rn(r, so), bv);
    }
    *(float4*)&out[((size_t)nimg * COUTc + co) * LSP + l] = o;
  }
}

extern "C" void kernel_launch(void* const* d_in, const int* in_sizes, int n_in,
                              void* d_out, int out_size, void* d_ws, size_t ws_size,
                              hipStream_t stream) {
  const float* x    = (const float*)d_in[0];
  const float* w    = (const float*)d_in[1];
  const float* bias = (const float*)d_in[2];
  float* out = (float*)d_out;
  char* ws = (char*)d_ws;

  k_prep<<<256, 256, 0, stream>>>(x, w, ws);
  k_quant<<<NB * Hc, 1024, 0, stream>>>(x, ws);
  k_gemm<<<196, 512, 0, stream>>>(ws);
  k_maxval<<<512, 256, 0, stream>>>(ws);
  k_final<<<dim3(MD / 64, COUTc / 64), 256, 0, stream>>>(bias, out, ws);
}